// Round 1
// baseline (1140.031 us; speedup 1.0000x reference)
//
#include <hip/hip_runtime.h>

#define N_ 4
#define C_ 32
#define L_ 8
#define D_ 24
#define H_ 24
#define W_ 24

// out[n,co,l,d,h,w] = bias[co] + sum_{ci, ql,qd,qh,qw in [0,3)}
//     x[n,ci,l+ql-1, d+qd-1, h+qh-1, w+qw-1] * wgt[ci,co, 2-ql,2-qd,2-qh,2-qw]
//
// Block: 384 threads, one (n,l,d), full 24x24 plane, all 32 co.
// Thread: 4 co x 12 w (one h row half). Per-ci: x halo tile + flipped
// weight slice staged in LDS.

__global__ __launch_bounds__(384) void convt4d_kernel(
    const float* __restrict__ x, const float* __restrict__ wgt,
    const float* __restrict__ bias, float* __restrict__ out)
{
    __shared__ float xs[9][26][28];   // [ql*3+qd][h+1][w+1], cols 26,27 zero pad
    __shared__ float ws[81][32];      // [flipped tap][co]

    const int t   = threadIdx.x;
    const int bid = blockIdx.x;
    const int n   = bid / (L_ * D_);
    const int rem = bid % (L_ * D_);
    const int l   = rem / D_;
    const int d   = rem % D_;

    const int cg  = t & 7;           // co group of 4
    const int px  = t >> 3;          // 0..47
    const int hr  = px >> 1;         // output row 0..23
    const int w0  = (px & 1) * 12;   // 0 or 12
    const int co0 = cg * 4;

    float acc[4][12];
#pragma unroll
    for (int a = 0; a < 4; ++a)
#pragma unroll
        for (int b = 0; b < 12; ++b) acc[a][b] = 0.f;

    const float* xn = x + (size_t)n * (C_ * L_ * D_ * H_ * W_);

#pragma unroll 1
    for (int ci = 0; ci < C_; ++ci) {
        __syncthreads();
        // ---- stage x halo tile: 9 planes x 26 rows x 28 cols ----
        const float* xc = xn + ci * (L_ * D_ * H_ * W_);
        for (int i = t; i < 9 * 26 * 28; i += 384) {
            int c  = i % 28;
            int rr = (i / 28) % 26;
            int p  = i / (28 * 26);
            int pl = p / 3, pd = p - pl * 3;
            int lx = l - 1 + pl, dx = d - 1 + pd, hx = rr - 1, wx = c - 1;
            float v = 0.f;
            if (lx >= 0 && lx < L_ && dx >= 0 && dx < D_ &&
                hx >= 0 && hx < H_ && wx >= 0 && wx < W_)
                v = xc[((lx * D_ + dx) * H_ + hx) * W_ + wx];
            (&xs[0][0][0])[i] = v;
        }
        // ---- stage flipped weights: ws[tap][co] = wgt[ci,co,80-tap] ----
        const float* wc = wgt + ci * (C_ * 81);
        for (int i = t; i < 81 * 32; i += 384) {
            int co  = i & 31;
            int tap = i >> 5;
            ws[tap][co] = wc[co * 81 + (80 - tap)];
        }
        __syncthreads();

        // ---- compute ----
#pragma unroll 1
        for (int qp = 0; qp < 9; ++qp) {
            const float* plane = &xs[qp][0][0];
#pragma unroll
            for (int qh = 0; qh < 3; ++qh) {
                const float* xrow = plane + (hr + qh) * 28 + w0;
                float xr[16];
                *(float4*)&xr[0]  = *(const float4*)(xrow);
                *(float4*)&xr[4]  = *(const float4*)(xrow + 4);
                *(float4*)&xr[8]  = *(const float4*)(xrow + 8);
                *(float4*)&xr[12] = *(const float4*)(xrow + 12);
#pragma unroll
                for (int qw = 0; qw < 3; ++qw) {
                    const int tap = (qp * 3 + qh) * 3 + qw;
                    float4 wv = *(const float4*)&ws[tap][co0];
                    float wvv[4] = {wv.x, wv.y, wv.z, wv.w};
#pragma unroll
                    for (int a = 0; a < 4; ++a)
#pragma unroll
                        for (int b = 0; b < 12; ++b)
                            acc[a][b] = fmaf(xr[b + qw], wvv[a], acc[a][b]);
                }
            }
        }
    }

    // ---- epilogue: bias + store ----
    const float4 bv = *(const float4*)(bias + co0);
    float bb[4] = {bv.x, bv.y, bv.z, bv.w};
#pragma unroll
    for (int a = 0; a < 4; ++a) {
        const int co = co0 + a;
        size_t off = ((((size_t)n * C_ + co) * L_ + l) * D_ + d) * (size_t)(H_ * W_)
                   + (size_t)hr * W_ + w0;
        float4 o0, o1, o2;
        o0.x = acc[a][0] + bb[a];  o0.y = acc[a][1] + bb[a];
        o0.z = acc[a][2] + bb[a];  o0.w = acc[a][3] + bb[a];
        o1.x = acc[a][4] + bb[a];  o1.y = acc[a][5] + bb[a];
        o1.z = acc[a][6] + bb[a];  o1.w = acc[a][7] + bb[a];
        o2.x = acc[a][8] + bb[a];  o2.y = acc[a][9] + bb[a];
        o2.z = acc[a][10] + bb[a]; o2.w = acc[a][11] + bb[a];
        *(float4*)(out + off)     = o0;
        *(float4*)(out + off + 4) = o1;
        *(float4*)(out + off + 8) = o2;
    }
}

extern "C" void kernel_launch(void* const* d_in, const int* in_sizes, int n_in,
                              void* d_out, int out_size, void* d_ws, size_t ws_size,
                              hipStream_t stream) {
    const float* x    = (const float*)d_in[0];
    const float* wgt  = (const float*)d_in[1];
    const float* bias = (const float*)d_in[2];
    float* out = (float*)d_out;

    dim3 grid(N_ * L_ * D_);   // 768 blocks: one per (n,l,d)
    dim3 block(384);
    convt4d_kernel<<<grid, block, 0, stream>>>(x, wgt, bias, out);
}

// Round 2
// 438.737 us; speedup vs baseline: 2.5984x; 2.5984x over previous
//
#include <hip/hip_runtime.h>

#define NN 4
#define CC 32
#define LL 8
#define DD 24
#define HH 24
#define WW 24

typedef short  bf16x8  __attribute__((ext_vector_type(8)));   // 8 bf16 in 4 VGPRs
typedef float  f32x16  __attribute__((ext_vector_type(16)));

__device__ __forceinline__ unsigned short f2bf(float f) {
    union { float f; unsigned u; } v; v.f = f;
    unsigned r = v.u + 0x7FFFu + ((v.u >> 16) & 1u);   // RNE
    return (unsigned short)(r >> 16);
}

// byte offset inside xs for tap-in-ql-slice tau = qd*9+qh*3+qw
constexpr int offb(int tau) {
    return ((tau / 9) * 676 + ((tau / 3) % 3) * 26 + (tau % 3)) * 16;
}

// out[n,co,l,d,h,w] = bias[co] + sum_{ci,t} wgt[ci,co,80-t] * x[n,ci,l+ql-1,d+qd-1,h+qh-1,w+qw-1]
// GEMM: A[co][k]=flipped wgt (M=32), B[k][pos]=shifted x (N=pos), K=(ci,tap).
// K-step = 16 = 8ci (j, ds_read_b128-contiguous) x 2 taps (lane group g).
__global__ __launch_bounds__(384, 3) void convt4d_mfma(
    const float* __restrict__ x, const float* __restrict__ wgt,
    const float* __restrict__ bias, float* __restrict__ out)
{
    __shared__ unsigned short xs[16224];  // [qd 3][h' 26][w' 26][ci 8] bf16
    __shared__ unsigned short As[7168];   // [s 14][lane 64][j 8]     bf16

    // XCD-aware bijective swizzle (768 % 8 == 0): 96 consecutive blocks per XCD
    int bid = (int)blockIdx.x;
    bid = (bid & 7) * 96 + (bid >> 3);
    const int n = bid / (LL * DD);
    const int l = (bid / DD) % LL;
    const int d = bid % DD;

    const int t    = (int)threadIdx.x;
    const int lane = t & 63;
    const int wave = t >> 6;           // 0..5
    const int g    = lane >> 5;        // k-group (tap selector)
    const int dh   = (lane >> 3) & 3;  // pos-in-tile h   (col = lane&31)
    const int dw   = lane & 7;         // pos-in-tile w
    const int h0   = wave * 4;         // wave owns rows h0..h0+3, all 24 w

    f32x16 acc[3];
#pragma unroll
    for (int i = 0; i < 3; ++i)
#pragma unroll
        for (int j = 0; j < 16; ++j) acc[i][j] = 0.f;

    const int base0 = ((h0 + dh) * 26 + dw) * 16;   // byte base into xs
    const char* xsb = (const char*)xs;

#pragma unroll 1
    for (int cig = 0; cig < 4; ++cig) {
#pragma unroll 1
        for (int ql = 0; ql < 3; ++ql) {
            const int lx = l + ql - 1;
            if (lx < 0 || lx >= LL) continue;      // block-uniform: whole slice is zero

            __syncthreads();                        // protect xs/As from previous stage readers

            // ---- stage x halo slice -> xs (bf16, ci-inner) ----
            for (int i = t; i < 16224; i += 384) {
                int ci = i & 7;
                int rr = i >> 3;
                int w2 = rr % 26;
                int r3 = rr / 26;
                int h2 = r3 % 26;
                int qd = r3 / 26;
                int dx = d + qd - 1, hx = h2 - 1, wx = w2 - 1;
                float v = 0.f;
                if ((unsigned)dx < DD && (unsigned)hx < HH && (unsigned)wx < WW)
                    v = x[(((((size_t)n * CC + (cig * 8 + ci)) * LL + lx) * DD + dx) * HH + hx) * WW + wx];
                xs[i] = f2bf(v);
            }
            // ---- stage flipped weights -> As in fragment order ----
            for (int i = t; i < 7168; i += 384) {
                int j   = i & 7;            // ci offset
                int ln  = (i >> 3) & 63;    // lane
                int s   = i >> 9;           // k-step 0..13
                int co  = ln & 31, gg = ln >> 5;
                int tau = 2 * s + gg;
                unsigned short v = 0;
                if (tau <= 26)
                    v = f2bf(wgt[(size_t)((cig * 8 + j) * CC + co) * 81 + 80 - (ql * 27 + tau)]);
                As[i] = v;
            }
            __syncthreads();

            // ---- MFMA sweep: 14 k-steps x 3 n-tiles ----
#pragma unroll
            for (int s = 0; s < 14; ++s) {
                bf16x8 a = *reinterpret_cast<const bf16x8*>(&As[(s * 64 + lane) * 8]);
                const int t0 = (2 * s     > 26) ? 26 : 2 * s;
                const int t1 = (2 * s + 1 > 26) ? 26 : 2 * s + 1;
                const int off = g ? offb(t1) : offb(t0);   // dummy slot: A==0 kills it
                const char* bp = xsb + (base0 + off);
#pragma unroll
                for (int nt = 0; nt < 3; ++nt) {
                    bf16x8 b = *reinterpret_cast<const bf16x8*>(bp + nt * 128);
                    acc[nt] = __builtin_amdgcn_mfma_f32_32x32x16_bf16(a, b, acc[nt], 0, 0, 0);
                }
            }
        }
    }

    // ---- epilogue: bias + store (C/D: col=lane&31 -> pos, row -> co) ----
#pragma unroll
    for (int r = 0; r < 16; ++r) {
        const int co = (r & 3) + 8 * (r >> 2) + 4 * g;
        const float bv = bias[co];
        size_t ob = (((((size_t)n * CC + co) * LL + l) * DD + d) * HH + (h0 + dh)) * WW + dw;
        out[ob]      = acc[0][r] + bv;
        out[ob + 8]  = acc[1][r] + bv;
        out[ob + 16] = acc[2][r] + bv;
    }
}

extern "C" void kernel_launch(void* const* d_in, const int* in_sizes, int n_in,
                              void* d_out, int out_size, void* d_ws, size_t ws_size,
                              hipStream_t stream) {
    const float* x    = (const float*)d_in[0];
    const float* wgt  = (const float*)d_in[1];
    const float* bias = (const float*)d_in[2];
    float* out = (float*)d_out;

    dim3 grid(NN * LL * DD);   // 768 = one block per (n,l,d)
    dim3 block(384);
    convt4d_mfma<<<grid, block, 0, stream>>>(x, wgt, bias, out);
}

// Round 3
// 104.790 us; speedup vs baseline: 10.8792x; 4.1868x over previous
//
#include <hip/hip_runtime.h>

#define NN 4
#define CC 32
#define LL 8
#define DD 24
#define HH 24
#define WW 24

typedef short  bf16x8  __attribute__((ext_vector_type(8)));
typedef float  f32x16  __attribute__((ext_vector_type(16)));
typedef unsigned short ushort8 __attribute__((ext_vector_type(8)));

// Workspace layout (requires ws_size >= 36,081,664 bytes ~= 34.4 MiB):
//   xp: [cig 4][n 4][l 8][d' 26][h' 26][w' 26][ci 8] bf16  (pre-padded halo,
//       zeros baked in; 16B chunk = one (pixel, 8ci) group) = 2,249,728 chunks
//   Ag: [cig 4][ql 3][s 14][lane 64][j 8] bf16 (flipped weights, MFMA
//       fragment order) = 43,008 elems
#define XP_CHUNKS (4 * 4 * 8 * 26 * 26 * 26)   // 2,249,728
#define XP_ELEMS  (XP_CHUNKS * 8)
#define AS_ELEMS  (4 * 3 * 14 * 64 * 8)        // 43,008

__device__ __forceinline__ unsigned short f2bf(float f) {
    union { float f; unsigned u; } v; v.f = f;
    unsigned r = v.u + 0x7FFFu + ((v.u >> 16) & 1u);   // RNE
    return (unsigned short)(r >> 16);
}

__device__ __forceinline__ void gload16(const void* g, void* l) {
    __builtin_amdgcn_global_load_lds(
        (const __attribute__((address_space(1))) unsigned int*)g,
        (__attribute__((address_space(3))) unsigned int*)l, 16, 0, 0);
}

// ---- pre-pass A: x (f32, NCLDHW) -> xp (bf16, padded, ci-inner) ----
__global__ __launch_bounds__(256) void prep_x(const float* __restrict__ x,
                                              unsigned short* __restrict__ xp) {
    const int c  = blockIdx.x * 256 + threadIdx.x;      // chunk id, grid exact
    const int wp = c % 26;
    const int t1 = c / 26;
    const int hp = t1 % 26;
    const int t2 = t1 / 26;
    const int dp = t2 % 26;
    const int t3 = t2 / 26;          // (cig*4 + n)*8 + l
    const int l  = t3 & 7;
    const int t4 = t3 >> 3;
    const int n  = t4 & 3;
    const int cig = t4 >> 2;
    const int dx = dp - 1, hx = hp - 1, wx = wp - 1;
    ushort8 v = {0, 0, 0, 0, 0, 0, 0, 0};
    if ((unsigned)dx < DD && (unsigned)hx < HH && (unsigned)wx < WW) {
        const float* src = x + (((((size_t)n * CC + cig * 8) * LL + l) * DD + dx) * HH + hx) * WW + wx;
#pragma unroll
        for (int ci = 0; ci < 8; ++ci)
            v[ci] = f2bf(src[(size_t)ci * (LL * DD * HH * WW)]);
    }
    *reinterpret_cast<ushort8*>(xp + (size_t)c * 8) = v;
}

// ---- pre-pass B: wgt (f32) -> Ag (bf16, flipped, fragment order) ----
__global__ __launch_bounds__(256) void prep_w(const float* __restrict__ wgt,
                                              unsigned short* __restrict__ Ag) {
    const int i  = blockIdx.x * 256 + threadIdx.x;      // grid exact (43008)
    const int j  = i & 7;
    const int ln = (i >> 3) & 63;
    const int r  = i >> 9;           // cig*42 + ql*14 + s
    const int s  = r % 14;
    const int r2 = r / 14;
    const int ql = r2 % 3;
    const int cig = r2 / 3;
    const int co = ln & 31, gg = ln >> 5, tau = 2 * s + gg;
    unsigned short v = 0;
    if (tau <= 26)
        v = f2bf(wgt[(size_t)((cig * 8 + j) * CC + co) * 81 + 80 - (ql * 27 + tau)]);
    Ag[i] = v;
}

// byte offset inside xs for tap-in-ql-slice tau = qd*9+qh*3+qw
constexpr int offb(int tau) {
    return ((tau / 9) * 676 + ((tau / 3) % 3) * 26 + (tau % 3)) * 16;
}

// GEMM: A[co][k]=flipped wgt (M=32), B[k][pos]=shifted x, K=(ci,tap).
// K-step = 16 = 8ci (j, contiguous) x 2 taps (lane group g).
__global__ __launch_bounds__(384, 4) void convt4d_main(
    const unsigned short* __restrict__ xp, const unsigned short* __restrict__ Ag,
    const float* __restrict__ bias, float* __restrict__ out)
{
    __shared__ __align__(16) unsigned short xs[2028 * 8];   // 32,448 B
    __shared__ __align__(16) unsigned short As[896 * 8];    // 14,336 B

    // XCD-aware bijective swizzle (768 % 8 == 0)
    int bid = (int)blockIdx.x;
    bid = (bid & 7) * 96 + (bid >> 3);
    const int n = bid / (LL * DD);
    const int l = (bid / DD) % LL;
    const int d = bid % DD;

    const int t    = (int)threadIdx.x;
    const int lane = t & 63;
    const int wave = t >> 6;           // 0..5
    const int g    = lane >> 5;        // k-group (tap selector)
    const int dh   = (lane >> 3) & 3;
    const int dw   = lane & 7;
    const int h0   = wave * 4;

    f32x16 acc[3];
#pragma unroll
    for (int i = 0; i < 3; ++i)
#pragma unroll
        for (int j = 0; j < 16; ++j) acc[i][j] = 0.f;

    const int base0 = ((h0 + dh) * 26 + dw) * 16;
    const char* xsb = (const char*)xs;

#pragma unroll 1
    for (int cig = 0; cig < 4; ++cig) {
#pragma unroll 1
        for (int ql = 0; ql < 3; ++ql) {
            const int lx = l + ql - 1;
            if (lx < 0 || lx >= LL) continue;      // block-uniform skip

            __syncthreads();   // previous stage fully consumed

            // ---- stage x: one contiguous 32,448 B region ----
            const unsigned short* xsrc =
                xp + (size_t)((((cig * 4 + n) * 8 + lx) * 26 + d)) * 676 * 8;
#pragma unroll
            for (int k0 = 0; k0 < 2028; k0 += 384) {
                int k = k0 + t;
                if (k0 + 384 <= 2028 || k < 2028)
                    gload16(xsrc + (size_t)k * 8, (char*)xs + (size_t)k * 16);
            }
            // ---- stage A: one contiguous 14,336 B region ----
            const unsigned short* asrc = Ag + (size_t)(cig * 3 + ql) * 7168;
#pragma unroll
            for (int k0 = 0; k0 < 896; k0 += 384) {
                int k = k0 + t;
                if (k0 + 384 <= 896 || k < 896)
                    gload16(asrc + (size_t)k * 8, (char*)As + (size_t)k * 16);
            }
            __syncthreads();   // waits vmcnt(0): LDS populated

            // ---- MFMA sweep: 14 k-steps x 3 n-tiles ----
#pragma unroll
            for (int s = 0; s < 14; ++s) {
                bf16x8 a = *reinterpret_cast<const bf16x8*>(&As[(s * 64 + lane) * 8]);
                const int t0 = (2 * s     > 26) ? 26 : 2 * s;
                const int t1 = (2 * s + 1 > 26) ? 26 : 2 * s + 1;
                const int off = g ? offb(t1) : offb(t0);   // dummy slot: A==0 kills it
                const char* bp = xsb + (base0 + off);
#pragma unroll
                for (int nt = 0; nt < 3; ++nt) {
                    bf16x8 b = *reinterpret_cast<const bf16x8*>(bp + nt * 128);
                    acc[nt] = __builtin_amdgcn_mfma_f32_32x32x16_bf16(a, b, acc[nt], 0, 0, 0);
                }
            }
        }
    }

    // ---- epilogue: bias + store (C/D: col=lane&31 -> pos, row -> co) ----
#pragma unroll
    for (int r = 0; r < 16; ++r) {
        const int co = (r & 3) + 8 * (r >> 2) + 4 * g;
        const float bv = bias[co];
        size_t ob = (((((size_t)n * CC + co) * LL + l) * DD + d) * HH + (h0 + dh)) * WW + dw;
        out[ob]      = acc[0][r] + bv;
        out[ob + 8]  = acc[1][r] + bv;
        out[ob + 16] = acc[2][r] + bv;
    }
}

extern "C" void kernel_launch(void* const* d_in, const int* in_sizes, int n_in,
                              void* d_out, int out_size, void* d_ws, size_t ws_size,
                              hipStream_t stream) {
    const float* x    = (const float*)d_in[0];
    const float* wgt  = (const float*)d_in[1];
    const float* bias = (const float*)d_in[2];
    float* out = (float*)d_out;

    unsigned short* xp = (unsigned short*)d_ws;
    unsigned short* Ag = xp + XP_ELEMS;

    prep_x<<<XP_CHUNKS / 256, 256, 0, stream>>>(x, xp);          // 8788 blocks
    prep_w<<<AS_ELEMS / 256, 256, 0, stream>>>(wgt, Ag);         // 168 blocks
    convt4d_main<<<NN * LL * DD, 384, 0, stream>>>(xp, Ag, bias, out);
}

// Round 4
// 99.139 us; speedup vs baseline: 11.4993x; 1.0570x over previous
//
#include <hip/hip_runtime.h>

#define NN 4
#define CC 32
#define LL 8
#define DD 24
#define HH 24
#define WW 24

typedef short  bf16x8  __attribute__((ext_vector_type(8)));
typedef float  f32x16  __attribute__((ext_vector_type(16)));
typedef unsigned short ushort8 __attribute__((ext_vector_type(8)));

// Workspace (requires ws_size >= 36,179,968 B ~= 34.5 MiB):
//   xp: [cig 4][n 4][l 8][d' 26][h' 26][w' 26][ci 8] bf16 (padded halo)
//   Ag: [cig 4][ql 3][qd 3][s 5][lane 64][j 8] bf16 (flipped wgt, frag order)
#define XP_CHUNKS (4 * 4 * 8 * 26 * 26 * 26)   // 2,249,728 16B chunks
#define XP_ELEMS  (XP_CHUNKS * 8)
#define AG_ELEMS  (4 * 3 * 3 * 5 * 64 * 8)     // 92,160

__device__ __forceinline__ unsigned short f2bf(float f) {
    union { float f; unsigned u; } v; v.f = f;
    unsigned r = v.u + 0x7FFFu + ((v.u >> 16) & 1u);   // RNE
    return (unsigned short)(r >> 16);
}

__device__ __forceinline__ void gload16(const void* g, void* l) {
    __builtin_amdgcn_global_load_lds(
        (const __attribute__((address_space(1))) unsigned int*)g,
        (__attribute__((address_space(3))) unsigned int*)l, 16, 0, 0);
}

// ---- pre-pass A: x (f32, NCLDHW) -> xp (bf16, padded, ci-inner) ----
__global__ __launch_bounds__(256) void prep_x(const float* __restrict__ x,
                                              unsigned short* __restrict__ xp) {
    const int c  = blockIdx.x * 256 + threadIdx.x;
    const int wp = c % 26;
    const int t1 = c / 26;
    const int hp = t1 % 26;
    const int t2 = t1 / 26;
    const int dp = t2 % 26;
    const int t3 = t2 / 26;          // (cig*4 + n)*8 + l
    const int l  = t3 & 7;
    const int t4 = t3 >> 3;
    const int n  = t4 & 3;
    const int cig = t4 >> 2;
    const int dx = dp - 1, hx = hp - 1, wx = wp - 1;
    ushort8 v = {0, 0, 0, 0, 0, 0, 0, 0};
    if ((unsigned)dx < DD && (unsigned)hx < HH && (unsigned)wx < WW) {
        const float* src = x + (((((size_t)n * CC + cig * 8) * LL + l) * DD + dx) * HH + hx) * WW + wx;
#pragma unroll
        for (int ci = 0; ci < 8; ++ci)
            v[ci] = f2bf(src[(size_t)ci * (LL * DD * HH * WW)]);
    }
    *reinterpret_cast<ushort8*>(xp + (size_t)c * 8) = v;
}

// ---- pre-pass B: wgt -> Ag, per-(cig,ql,qd) 5-step fragment blocks ----
__global__ __launch_bounds__(256) void prep_w(const float* __restrict__ wgt,
                                              unsigned short* __restrict__ Ag) {
    const int i  = blockIdx.x * 256 + threadIdx.x;   // grid exact (92160)
    const int j  = i & 7;
    const int ln = (i >> 3) & 63;
    const int s  = (i >> 9) % 5;
    const int r  = (i >> 9) / 5;     // (cig*3+ql)*3+qd
    const int qd = r % 3;
    const int ql = (r / 3) % 3;
    const int cig = r / 9;
    const int co = ln & 31, gg = ln >> 5;
    const int tl = 2 * s + gg;       // tau within qd-plane: qh*3+qw
    unsigned short v = 0;
    if (tl <= 8) {
        const int tap = ql * 27 + qd * 9 + tl;
        v = f2bf(wgt[(size_t)((cig * 8 + j) * CC + co) * 81 + 80 - tap]);
    }
    Ag[i] = v;
}

// GEMM: A[co][k]=flipped wgt (M=32), B[k][pos]=shifted x, K=(ci,tap).
// K-step = 16 = 8ci x 2 taps (lane group g). Stage granularity = one
// (cig,ql,qd) input plane (10.8 KB) + its A block (5.1 KB), double-buffered
// with a 2-phase pipeline: issue t+1 -> compute t -> barrier.
__global__ __launch_bounds__(384, 4) void convt4d_main(
    const unsigned short* __restrict__ xp, const unsigned short* __restrict__ Ag,
    const float* __restrict__ bias, float* __restrict__ out)
{
    __shared__ __align__(16) unsigned short xs[2][676 * 8];   // 2 x 10,816 B
    __shared__ __align__(16) unsigned short As[2][320 * 8];   // 2 x  5,120 B

    // XCD-aware bijective swizzle (768 % 8 == 0)
    int bid = (int)blockIdx.x;
    bid = (bid & 7) * 96 + (bid >> 3);
    const int n = bid / (LL * DD);
    const int l = (bid / DD) % LL;
    const int d = bid % DD;

    const int t    = (int)threadIdx.x;
    const int lane = t & 63;
    const int wave = t >> 6;           // 0..5
    const int g    = lane >> 5;        // tap selector
    const int dh   = (lane >> 3) & 3;
    const int dw   = lane & 7;
    const int h0   = wave * 4;

    const int ql0 = (l == 0) ? 1 : 0;
    const int nql = 3 - (l == 0) - (l == 7);
    const int nst = 4 * nql * 3;       // stages: (cig, valid ql, qd)

    f32x16 acc[3];
#pragma unroll
    for (int i = 0; i < 3; ++i)
#pragma unroll
        for (int j = 0; j < 16; ++j) acc[i][j] = 0.f;

    const int base0 = ((h0 + dh) * 26 + dw) * 16;

    auto issue = [&](int id, int buf) {
        const int qd  = id % 3;
        const int r   = id / 3;
        const int ql  = ql0 + r % nql;
        const int cig = r / nql;
        const int lx  = l + ql - 1;
        const unsigned short* xsrc =
            xp + (size_t)((((cig * 4 + n) * 8 + lx) * 26) + (d + qd)) * (676 * 8);
        gload16(xsrc + (size_t)t * 8, (char*)xs[buf] + (size_t)t * 16);
        if (t + 384 < 676)
            gload16(xsrc + (size_t)(t + 384) * 8, (char*)xs[buf] + (size_t)(t + 384) * 16);
        const unsigned short* asrc = Ag + (size_t)((cig * 3 + ql) * 3 + qd) * 2560;
        if (t < 320)
            gload16(asrc + (size_t)t * 8, (char*)As[buf] + (size_t)t * 16);
    };

    issue(0, 0);

#pragma unroll 1
    for (int st = 0; st < nst; ++st) {
        const int buf = st & 1;
        __syncthreads();               // stage st landed; buf^1 fully consumed
        if (st + 1 < nst) issue(st + 1, buf ^ 1);

        const char* xsb = (const char*)xs[buf];
#pragma unroll
        for (int s = 0; s < 5; ++s) {
            bf16x8 a = *reinterpret_cast<const bf16x8*>(&As[buf][(s * 64 + lane) * 8]);
            const int t0 = 2 * s;
            const int t1 = (2 * s + 1 > 8) ? 8 : 2 * s + 1;  // clamp dummy in-bounds
            const int tl = g ? t1 : t0;
            const int off = ((tl / 3) * 26 + (tl % 3)) * 16;
            const char* bp = xsb + (base0 + off);
#pragma unroll
            for (int nt = 0; nt < 3; ++nt) {
                bf16x8 b = *reinterpret_cast<const bf16x8*>(bp + nt * 128);
                acc[nt] = __builtin_amdgcn_mfma_f32_32x32x16_bf16(a, b, acc[nt], 0, 0, 0);
            }
        }
    }

    // ---- epilogue: bias + store (C/D: col=lane&31 -> pos, row -> co) ----
#pragma unroll
    for (int r = 0; r < 16; ++r) {
        const int co = (r & 3) + 8 * (r >> 2) + 4 * g;
        const float bv = bias[co];
        size_t ob = (((((size_t)n * CC + co) * LL + l) * DD + d) * HH + (h0 + dh)) * WW + dw;
        out[ob]      = acc[0][r] + bv;
        out[ob + 8]  = acc[1][r] + bv;
        out[ob + 16] = acc[2][r] + bv;
    }
}

extern "C" void kernel_launch(void* const* d_in, const int* in_sizes, int n_in,
                              void* d_out, int out_size, void* d_ws, size_t ws_size,
                              hipStream_t stream) {
    const float* x    = (const float*)d_in[0];
    const float* wgt  = (const float*)d_in[1];
    const float* bias = (const float*)d_in[2];
    float* out = (float*)d_out;

    unsigned short* xp = (unsigned short*)d_ws;
    unsigned short* Ag = xp + XP_ELEMS;

    prep_x<<<XP_CHUNKS / 256, 256, 0, stream>>>(x, xp);     // 8788 blocks
    prep_w<<<AG_ELEMS / 256, 256, 0, stream>>>(wgt, Ag);    // 360 blocks
    convt4d_main<<<NN * LL * DD, 384, 0, stream>>>(xp, Ag, bias, out);
}